// Round 16
// baseline (455.801 us; speedup 1.0000x reference)
//
#include <hip/hip_runtime.h>
#include <math.h>

#define S_LEN 2048
#define BSZ 2
#define DM 512
#define NH 8
#define HD 64
#define RTOT (S_LEN*BSZ)             // 4096 rows, row r = s*BSZ + b
#define T_KEEP 32
#define ROW0 ((S_LEN - T_KEEP)*BSZ)  // 4032
#define NXELEM (RTOT*DM)             // 2097152
#define NWROW  (NH*128)              // 1024 (per-head q|k rows)
#define NWELEM (NWROW*DM)            // 524288
#define GRID   512
#define NTHR   (GRID*256)

typedef __attribute__((ext_vector_type(8))) _Float16 half8;
typedef __attribute__((ext_vector_type(4))) float floatx4;

__device__ __forceinline__ void gld16(const void* g, void* l) {
    __builtin_amdgcn_global_load_lds((const __attribute__((address_space(1))) void*)g,
                                     (__attribute__((address_space(3))) void*)l, 16, 0, 0);
}

__device__ __forceinline__ short cvt1(float v) {
    _Float16 h = (_Float16)v;
    return __builtin_bit_cast(short, h);
}

// Manual grid barrier: release fence -> arrive -> bounded spin -> acquire fence.
// Counters zeroed via hipMemsetAsync before launch. Bounded spin (never hangs):
// if co-residency fails the result is wrong, not a timeout.
__device__ __forceinline__ void gridbar(unsigned* cnt, int idx) {
    __syncthreads();
    __threadfence();
    if (threadIdx.x == 0) {
        atomicAdd(&cnt[idx], 1u);
        unsigned it = 0;
        while (atomicAdd(&cnt[idx], 0u) < (unsigned)GRID && it < 2000000u) {
            __builtin_amdgcn_s_sleep(8);
            ++it;
        }
    }
    __syncthreads();
    __threadfence();
}

// Persistent fused kernel: P0 convert/zero/fill -> P1 qk GEMM -> P2 sbar ->
// P3 head (kbar/vbar/coef/G) -> P4 out rows. Phase bodies = r11-sub (125.6us)
// versions verbatim; manual barriers replace 4 dispatch boundaries.
__global__ __launch_bounds__(256, 2) void fused(
    const float* __restrict__ x,
    const float* __restrict__ Wq, const float* __restrict__ bq,
    const float* __restrict__ Wk, const float* __restrict__ bk,
    const float* __restrict__ Wv, const float* __restrict__ bv,
    const float* __restrict__ Wo, const float* __restrict__ bo,
    const float* __restrict__ beta,
    short* __restrict__ xf, short* __restrict__ wf, float* __restrict__ bcat,
    float* __restrict__ sig, float* __restrict__ qsel,
    float* __restrict__ sbar, float* __restrict__ Ssum,
    float* __restrict__ coef, float* __restrict__ G,
    unsigned* __restrict__ cnt, float* __restrict__ out)
{
    __shared__ __align__(16) char smem[65536];
    const int bid = blockIdx.x;
    const int tid = threadIdx.x;

    // ---------------- P0: fp16 planes + bcat + zeros + background fill --------
    {
        const int g = bid*256 + tid;
        const int total4 = (NXELEM + NWELEM)/4;
        for (int i = g; i < total4; i += NTHR) {
            float4 v; size_t dst; short* d;
            if (i < NXELEM/4) {
                v = ((const float4*)x)[i];
                dst = (size_t)i*4; d = xf;
            } else {
                int e = (i - NXELEM/4)*4;
                int R = e >> 9;                 // h*128 + (q:0-63 | k:64-127)
                int k = e & 511;
                int h = R >> 7;
                int p = R & 127;
                int m = p >> 6;
                int c = p & 63;
                const float* W = m ? Wk : Wq;
                v = *(const float4*)&W[(size_t)(h*HD + c)*DM + k];
                dst = (size_t)R*DM + k; d = wf;
            }
            short4 hv;
            hv.x = cvt1(v.x); hv.y = cvt1(v.y); hv.z = cvt1(v.z); hv.w = cvt1(v.w);
            *(short4*)&d[dst] = hv;
        }
        {
            const float4* b4 = (const float4*)bo;
            float4* o4 = (float4*)out;
            const int fill4 = ROW0*DM/4;
            for (int i = g; i < fill4; i += NTHR) o4[i] = b4[i & 127];
        }
        if (g < NWROW) {
            int h = g >> 7, p = g & 127, m = p >> 6, c = p & 63;
            bcat[g] = (m ? bk : bq)[h*HD + c];
        }
        if (g < NH*RTOT) sig[g] = 0.f;
        if (g < 16*DM)   sbar[g] = 0.f;
        if (g < 16)      Ssum[g] = 0.f;
    }
    gridbar(cnt, 0);

    // ---------------- P1: fp16 MFMA q,k GEMM -> raw scores + qsel -------------
    {
        const int w    = tid >> 6;
        const int lane = tid & 63;
        const int lrow = lane & 15;
        const int lk8  = lane >> 4;
        const int rc   = bid & 31;
        const int h    = (bid >> 5) & 7;
        const int jh   = bid >> 8;
        const int r0   = rc * 128;

        {
            const int t = w;
            const int bcol = (t < 2) ? (jh*32 + t*16) : (64 + jh*32 + (t-2)*16);
            const short* src = wf + (size_t)(h*128 + bcol + lrow)*DM + lk8*8;
            for (int ci = 0; ci < 16; ++ci)
                gld16(src + ci*32, smem + (w*16 + ci)*1024);
        }
        __syncthreads();

        const float bq0 = bcat[h*128 + jh*32 + lrow];
        const float bq1 = bcat[h*128 + jh*32 + 16 + lrow];
        const float bk0 = bcat[h*128 + 64 + jh*32 + lrow];
        const float bk1 = bcat[h*128 + 64 + jh*32 + 16 + lrow];

        #pragma unroll
        for (int nn = 0; nn < 2; ++nn) {
            const int n = w + nn*4;
            const int rbase = r0 + n*16;

            half8 A[16];
            const short* pa = xf + (size_t)(rbase + lrow)*DM + lk8*8;
            #pragma unroll
            for (int kc = 0; kc < 16; ++kc)
                A[kc] = *(const half8*)(pa + kc*32);

            floatx4 aq0 = (floatx4)0.f, aq1 = (floatx4)0.f;
            floatx4 ak0 = (floatx4)0.f, ak1 = (floatx4)0.f;
            #pragma unroll
            for (int kc = 0; kc < 16; ++kc) {
                half8 b0 = *(const half8*)(smem + ( 0 + kc)*1024 + lane*16);
                half8 b1 = *(const half8*)(smem + (16 + kc)*1024 + lane*16);
                half8 b2 = *(const half8*)(smem + (32 + kc)*1024 + lane*16);
                half8 b3 = *(const half8*)(smem + (48 + kc)*1024 + lane*16);
                aq0 = __builtin_amdgcn_mfma_f32_16x16x32_f16(A[kc], b0, aq0, 0, 0, 0);
                aq1 = __builtin_amdgcn_mfma_f32_16x16x32_f16(A[kc], b1, aq1, 0, 0, 0);
                ak0 = __builtin_amdgcn_mfma_f32_16x16x32_f16(A[kc], b2, ak0, 0, 0, 0);
                ak1 = __builtin_amdgcn_mfma_f32_16x16x32_f16(A[kc], b3, ak1, 0, 0, 0);
            }

            #pragma unroll
            for (int r = 0; r < 4; ++r) {
                float q0 = aq0[r] + bq0, q1 = aq1[r] + bq1;
                float k0 = ak0[r] + bk0, k1 = ak1[r] + bk1;
                float p = q0*k0 + q1*k1;
                p += __shfl_xor(p, 1, 64);
                p += __shfl_xor(p, 2, 64);
                p += __shfl_xor(p, 4, 64);
                p += __shfl_xor(p, 8, 64);
                int row = rbase + lk8*4 + r;
                if (lrow == 0) atomicAdd(&sig[h*RTOT + row], p);
                if (((row >> 1) & 63) == 63) {
                    int b  = row & 1;
                    int wi = row >> 7;
                    float* qd = &qsel[((size_t)(b*NH + h)*T_KEEP + wi)*64];
                    qd[jh*32 + lrow]      = q0;
                    qd[jh*32 + 16 + lrow] = q1;
                }
            }
        }
    }
    gridbar(cnt, 1);

    // ---------------- P2: sigma = sigmoid; sbar += sigma*x; Ssum --------------
    if (bid < 64) {
        float* ss = (float*)smem;              // [64][8]
        const int b = bid & 1;
        const int s0 = (bid >> 1) * 64;

        for (int i = tid; i < 64*NH; i += 256) {
            int s = i >> 3, hh = i & 7;
            float raw = sig[hh*RTOT + (s0 + s)*2 + b];
            float isc = 1.0f / (8.0f * expf(beta[hh]));
            ss[s*8 + hh] = 1.0f / (1.0f + expf(-raw * isc));
        }
        __syncthreads();
        if (tid < NH) {
            float t = 0.f;
            for (int s = 0; s < 64; ++s) t += ss[s*8 + tid];
            atomicAdd(&Ssum[b*NH + tid], t);
        }
        #pragma unroll
        for (int cp = 0; cp < 2; ++cp) {
            int c = cp*256 + tid;
            float a8[NH];
            #pragma unroll
            for (int hh = 0; hh < NH; ++hh) a8[hh] = 0.f;
            for (int s = 0; s < 64; ++s) {
                float xv = x[(size_t)((s0 + s)*2 + b)*DM + c];
                #pragma unroll
                for (int hh = 0; hh < NH; ++hh) a8[hh] += ss[s*8 + hh] * xv;
            }
            #pragma unroll
            for (int hh = 0; hh < NH; ++hh)
                atomicAdd(&sbar[(b*NH + hh)*DM + c], a8[hh]);
        }
    }
    gridbar(cnt, 2);

    // ---------------- P3: kbar/vbar = W*sbar + b*S; coef softmax; G -----------
    if (bid < 16) {
        float* F = (float*)smem;
        float* s_sb   = F;            // 512
        float* s_red  = F + 512;      // 64*4
        float* s_kb   = F + 768;      // 64
        float* s_vb   = F + 832;      // 64
        float* s_part = F + 896;      // 32*8
        float* s_gp   = F + 1152;     // 64*4
        const int z = bid;
        const int h = z & 7;

        s_sb[tid]       = sbar[z*DM + tid];
        s_sb[tid + 256] = sbar[z*DM + 256 + tid];
        __syncthreads();
        const float S = Ssum[z];

        {
            int j = tid >> 2, kp = tid & 3;
            const float* wr = &Wk[(size_t)(h*HD + j)*DM + kp*128];
            float a = 0.f;
            #pragma unroll
            for (int k = 0; k < 128; k += 4) {
                float4 w4 = *(const float4*)&wr[k];
                int k0 = kp*128 + k;
                a += w4.x*s_sb[k0] + w4.y*s_sb[k0+1] + w4.z*s_sb[k0+2] + w4.w*s_sb[k0+3];
            }
            s_red[j*4 + kp] = a;
        }
        __syncthreads();
        if (tid < 64) s_kb[tid] = s_red[tid*4]+s_red[tid*4+1]+s_red[tid*4+2]+s_red[tid*4+3]
                                  + bk[h*HD + tid]*S;
        __syncthreads();
        {
            int j = tid >> 2, kp = tid & 3;
            const float* wr = &Wv[(size_t)(h*HD + j)*DM + kp*128];
            float a = 0.f;
            #pragma unroll
            for (int k = 0; k < 128; k += 4) {
                float4 w4 = *(const float4*)&wr[k];
                int k0 = kp*128 + k;
                a += w4.x*s_sb[k0] + w4.y*s_sb[k0+1] + w4.z*s_sb[k0+2] + w4.w*s_sb[k0+3];
            }
            s_red[j*4 + kp] = a;
        }
        __syncthreads();
        if (tid < 64) s_vb[tid] = s_red[tid*4]+s_red[tid*4+1]+s_red[tid*4+2]+s_red[tid*4+3]
                                  + bv[h*HD + tid]*S;
        __syncthreads();

        {
            int wi = tid >> 3, jg = tid & 7;
            const float* qrow = &qsel[((size_t)z*T_KEEP + wi)*64 + jg*8];
            float4 q1 = *(const float4*)qrow;
            float4 q2 = *(const float4*)(qrow + 4);
            int j0 = jg*8;
            float p = q1.x*s_kb[j0] + q1.y*s_kb[j0+1] + q1.z*s_kb[j0+2] + q1.w*s_kb[j0+3]
                    + q2.x*s_kb[j0+4] + q2.y*s_kb[j0+5] + q2.z*s_kb[j0+6] + q2.w*s_kb[j0+7];
            s_part[wi*8 + jg] = p;
        }
        __syncthreads();
        if (tid < T_KEEP) {
            float sc = 0.f;
            #pragma unroll
            for (int gg = 0; gg < 8; ++gg) sc += s_part[tid*8 + gg];
            sc *= 1.0f / (8.0f * expf(beta[h]));
            float m = sc;
            #pragma unroll
            for (int off = 16; off > 0; off >>= 1) m = fmaxf(m, __shfl_xor(m, off, 64));
            m = fmaxf(m, 0.f);                       // sink logit = 0
            float e = expf(sc - m);
            float d = e;
            #pragma unroll
            for (int off = 16; off > 0; off >>= 1) d += __shfl_xor(d, off, 64);
            d += expf(-m);                           // sink term
            float c = e / d;
            if (tid == T_KEEP-1) c += 1.0f;          // iter-0 contribution
            coef[z*T_KEEP + tid] = c;
        }

        const int cq = tid >> 2;
        const int jg = tid & 3;
        #pragma unroll
        for (int it = 0; it < 8; ++it) {
            int c = it*64 + cq;
            const float* wrow = &Wo[(size_t)c*DM + h*HD + jg*16];
            float a = 0.f;
            #pragma unroll
            for (int jj = 0; jj < 16; jj += 4) {
                float4 wv = *(const float4*)&wrow[jj];
                int j0 = jg*16 + jj;
                a += wv.x*s_vb[j0] + wv.y*s_vb[j0+1] + wv.z*s_vb[j0+2] + wv.w*s_vb[j0+3];
            }
            s_gp[cq*4 + jg] = a;
            __syncthreads();
            if (tid < 64)
                G[(size_t)z*DM + it*64 + tid] = s_gp[tid*4] + s_gp[tid*4+1] + s_gp[tid*4+2] + s_gp[tid*4+3];
            __syncthreads();
        }
    }
    gridbar(cnt, 3);

    // ---------------- P4: output rows from coef x G ---------------------------
    if (bid < 64) {
        float* s_cf = (float*)smem;
        const int a = bid;
        const int b = a & 1;
        const int wi = a >> 1;
        __syncthreads();
        if (tid < NH) s_cf[tid] = coef[(b*NH + tid)*T_KEEP + wi];
        __syncthreads();
        for (int c = tid; c < DM; c += 256) {
            float v = bo[c];
            #pragma unroll
            for (int h = 0; h < NH; ++h)
                v += s_cf[h] * G[(size_t)(b*NH + h)*DM + c];
            out[(size_t)(ROW0 + a)*DM + c] = v;
        }
    }
}

extern "C" void kernel_launch(void* const* d_in, const int* in_sizes, int n_in,
                              void* d_out, int out_size, void* d_ws, size_t ws_size,
                              hipStream_t stream) {
    const float* x    = (const float*)d_in[0];
    const float* Wq   = (const float*)d_in[1];
    const float* bq   = (const float*)d_in[2];
    const float* Wk   = (const float*)d_in[3];
    const float* bk   = (const float*)d_in[4];
    const float* Wv   = (const float*)d_in[5];
    const float* bv   = (const float*)d_in[6];
    const float* Wo   = (const float*)d_in[7];
    const float* bo   = (const float*)d_in[8];
    const float* beta = (const float*)d_in[9];

    char* ws = (char*)d_ws;
    float* sig  = (float*)(ws + 0);         // 128 KB [h][4096] raw scores
    float* qsel = (float*)(ws + 131072);    // 128 KB
    float* sbar = (float*)(ws + 262144);    //  32 KB [z][512]
    float* Ssum = (float*)(ws + 294912);    //  64 B
    float* bcat = (float*)(ws + 295168);    //   4 KB [h][128] (q|k)
    float* coef = (float*)(ws + 299264);    //   2 KB
    float* G    = (float*)(ws + 301312);    //  32 KB
    short* xf   = (short*)(ws + 335872);    //   4 MB
    short* wf   = (short*)(ws + 335872 + 4194304);   // 1 MB
    unsigned* cnt = (unsigned*)(ws + 335872 + 4194304 + 1048576);  // 16 B
    float* out  = (float*)d_out;

    hipMemsetAsync(cnt, 0, 4*sizeof(unsigned), stream);
    fused<<<GRID, 256, 0, stream>>>(x, Wq, bq, Wk, bk, Wv, bv, Wo, bo, beta,
                                    xf, wf, bcat, sig, qsel, sbar, Ssum,
                                    coef, G, cnt, out);
}

// Round 17
// 131.165 us; speedup vs baseline: 3.4750x; 3.4750x over previous
//
#include <hip/hip_runtime.h>
#include <math.h>

#define S_LEN 2048
#define BSZ 2
#define DM 512
#define NH 8
#define HD 64
#define RTOT (S_LEN*BSZ)             // 4096 rows, row r = s*BSZ + b
#define T_KEEP 32
#define ROW0 ((S_LEN - T_KEEP)*BSZ)  // 4032
#define NXELEM (RTOT*DM)             // 2097152
#define NWROW  (NH*128)              // 1024 (per-head q|k rows)
#define NWELEM (NWROW*DM)            // 524288

typedef __attribute__((ext_vector_type(8))) _Float16 half8;
typedef __attribute__((ext_vector_type(4))) float floatx4;

__device__ __forceinline__ void gld16(const void* g, void* l) {
    __builtin_amdgcn_global_load_lds((const __attribute__((address_space(1))) void*)g,
                                     (__attribute__((address_space(3))) void*)l, 16, 0, 0);
}

__device__ __forceinline__ short cvt1(float v) {
    _Float16 h = (_Float16)v;
    return __builtin_bit_cast(short, h);
}

// ---- Kernel 0: fp16 planes (x, Wq|Wk) + bcat + zeros + FULL out prefill -------
// Out rows >= ROW0 are initialized to bo here; headk_out atomically adds the
// attention contributions two dispatches later.
__global__ __launch_bounds__(256) void convert(
    const float* __restrict__ x,
    const float* __restrict__ Wq, const float* __restrict__ Wk,
    const float* __restrict__ bq, const float* __restrict__ bk,
    const float* __restrict__ bo,
    short* __restrict__ xf, short* __restrict__ wf, float* __restrict__ bcat,
    float* __restrict__ sig, float* __restrict__ sbar, float* __restrict__ Ssum,
    float* __restrict__ out)
{
    const int g = blockIdx.x*blockDim.x + threadIdx.x;
    const int stride = gridDim.x*blockDim.x;
    const int total4 = (NXELEM + NWELEM)/4;
    for (int i = g; i < total4; i += stride) {
        float4 v; size_t dst; short* d;
        if (i < NXELEM/4) {
            v = ((const float4*)x)[i];
            dst = (size_t)i*4; d = xf;
        } else {
            int e = (i - NXELEM/4)*4;
            int R = e >> 9;                 // h*128 + (q:0-63 | k:64-127)
            int k = e & 511;
            int h = R >> 7;
            int p = R & 127;
            int m = p >> 6;                 // 0=q, 1=k
            int c = p & 63;
            const float* W = m ? Wk : Wq;
            v = *(const float4*)&W[(size_t)(h*HD + c)*DM + k];
            dst = (size_t)R*DM + k; d = wf;
        }
        short4 hv;
        hv.x = cvt1(v.x); hv.y = cvt1(v.y); hv.z = cvt1(v.z); hv.w = cvt1(v.w);
        *(short4*)&d[dst] = hv;
    }
    // fill ALL rows of out with bo (attention rows get atomic adds later)
    {
        const float4* b4 = (const float4*)bo;
        float4* o4 = (float4*)out;
        const int fill4 = RTOT*DM/4;
        for (int i = g; i < fill4; i += stride) o4[i] = b4[i & 127];
    }
    if (g < NWROW) {
        int h = g >> 7, p = g & 127, m = p >> 6, c = p & 63;
        bcat[g] = (m ? bk : bq)[h*HD + c];
    }
    if (g < NH*RTOT) sig[g] = 0.f;      // 32768
    if (g < 16*DM)   sbar[g] = 0.f;     // 8192
    if (g < 16)      Ssum[g] = 0.f;
}

// ---- Kernel 1: fp16 MFMA q,k GEMM -> raw sigma scores (+qsel) -----------------
// grid (32 rowchunks, 8 heads, 2 j-halves): block = 128 rows x 32 j's (q&k).
// B staged in LDS ONCE (single barrier); A-frags from global; no main-loop
// barriers; sigma j-partials combined across blocks via global atomicAdd.
__global__ __launch_bounds__(256, 2) void qk_gemm(
    const _Float16* __restrict__ xf, const _Float16* __restrict__ wf,
    const float* __restrict__ bcat,
    float* __restrict__ sig, float* __restrict__ qsel)
{
    __shared__ __align__(16) char smem[65536];   // B: 64 chunks x 1KB

    const int tid  = threadIdx.x;
    const int w    = tid >> 6;
    const int lane = tid & 63;
    const int lrow = lane & 15;
    const int lk8  = lane >> 4;
    const int rc   = blockIdx.x;     // 0..31
    const int h    = blockIdx.y;     // 0..7
    const int jh   = blockIdx.z;     // 0..1
    const int r0   = rc * 128;

    {
        const int t = w;
        const int bcol = (t < 2) ? (jh*32 + t*16) : (64 + jh*32 + (t-2)*16);
        const _Float16* src = wf + (size_t)(h*128 + bcol + lrow)*DM + lk8*8;
        for (int ci = 0; ci < 16; ++ci)
            gld16(src + ci*32, smem + (w*16 + ci)*1024);
    }
    __syncthreads();

    const float bq0 = bcat[h*128 + jh*32 + lrow];
    const float bq1 = bcat[h*128 + jh*32 + 16 + lrow];
    const float bk0 = bcat[h*128 + 64 + jh*32 + lrow];
    const float bk1 = bcat[h*128 + 64 + jh*32 + 16 + lrow];

    #pragma unroll
    for (int nn = 0; nn < 2; ++nn) {
        const int n = w + nn*4;              // row-tile 0..7
        const int rbase = r0 + n*16;

        half8 A[16];
        const _Float16* pa = xf + (size_t)(rbase + lrow)*DM + lk8*8;
        #pragma unroll
        for (int kc = 0; kc < 16; ++kc)
            A[kc] = *(const half8*)(pa + kc*32);

        floatx4 aq0 = (floatx4)0.f, aq1 = (floatx4)0.f;
        floatx4 ak0 = (floatx4)0.f, ak1 = (floatx4)0.f;
        #pragma unroll
        for (int kc = 0; kc < 16; ++kc) {
            half8 b0 = *(const half8*)(smem + ( 0 + kc)*1024 + lane*16);
            half8 b1 = *(const half8*)(smem + (16 + kc)*1024 + lane*16);
            half8 b2 = *(const half8*)(smem + (32 + kc)*1024 + lane*16);
            half8 b3 = *(const half8*)(smem + (48 + kc)*1024 + lane*16);
            aq0 = __builtin_amdgcn_mfma_f32_16x16x32_f16(A[kc], b0, aq0, 0, 0, 0);
            aq1 = __builtin_amdgcn_mfma_f32_16x16x32_f16(A[kc], b1, aq1, 0, 0, 0);
            ak0 = __builtin_amdgcn_mfma_f32_16x16x32_f16(A[kc], b2, ak0, 0, 0, 0);
            ak1 = __builtin_amdgcn_mfma_f32_16x16x32_f16(A[kc], b3, ak1, 0, 0, 0);
        }

        #pragma unroll
        for (int r = 0; r < 4; ++r) {
            float q0 = aq0[r] + bq0, q1 = aq1[r] + bq1;
            float k0 = ak0[r] + bk0, k1 = ak1[r] + bk1;
            float p = q0*k0 + q1*k1;
            p += __shfl_xor(p, 1, 64);
            p += __shfl_xor(p, 2, 64);
            p += __shfl_xor(p, 4, 64);
            p += __shfl_xor(p, 8, 64);
            int row = rbase + lk8*4 + r;
            if (lrow == 0) atomicAdd(&sig[h*RTOT + row], p);
            if (((row >> 1) & 63) == 63) {
                int b  = row & 1;
                int wi = row >> 7;
                float* qd = &qsel[((size_t)(b*NH + h)*T_KEEP + wi)*64];
                qd[jh*32 + lrow]      = q0;
                qd[jh*32 + 16 + lrow] = q1;
            }
        }
    }
}

// ---- Kernel 2: sigma = sigmoid(raw*scale); sbar = sum sigma*x; Ssum -----------
__global__ __launch_bounds__(256) void sbark(
    const float* __restrict__ x, const float* __restrict__ sigr,
    const float* __restrict__ beta, float* __restrict__ sbar,
    float* __restrict__ Ssum)
{
    __shared__ float ss[64][NH];
    const int tid = threadIdx.x;
    const int b = blockIdx.x & 1;
    const int s0 = (blockIdx.x >> 1) * 64;

    for (int i = tid; i < 64*NH; i += 256) {
        int s = i >> 3, hh = i & 7;
        float raw = sigr[hh*RTOT + (s0 + s)*2 + b];
        float isc = 1.0f / (8.0f * expf(beta[hh]));
        ss[s][hh] = 1.0f / (1.0f + expf(-raw * isc));
    }
    __syncthreads();
    if (tid < NH) {
        float t = 0.f;
        for (int s = 0; s < 64; ++s) t += ss[s][tid];
        atomicAdd(&Ssum[b*NH + tid], t);
    }
    #pragma unroll
    for (int cp = 0; cp < 2; ++cp) {
        int c = cp*256 + tid;
        float a8[NH];
        #pragma unroll
        for (int hh = 0; hh < NH; ++hh) a8[hh] = 0.f;
        for (int s = 0; s < 64; ++s) {
            float xv = x[(size_t)((s0 + s)*2 + b)*DM + c];
            #pragma unroll
            for (int hh = 0; hh < NH; ++hh) a8[hh] += ss[s][hh] * xv;
        }
        #pragma unroll
        for (int hh = 0; hh < NH; ++hh)
            atomicAdd(&sbar[(b*NH + hh)*DM + c], a8[hh]);
    }
}

// ---- Kernel 3: kbar/vbar = W*sbar + b*S; coef softmax; G; atomic out ----------
// grid 16 (z = b*8+h), block 256. Instead of writing G/coef and running a 4th
// kernel, each z-block atomically adds coef[wi]*G[c] into out rows directly
// (rows pre-filled with bo by convert).
__global__ __launch_bounds__(256) void headk_out(
    const float* __restrict__ qsel, const float* __restrict__ beta,
    const float* __restrict__ sbar, const float* __restrict__ Ssum,
    const float* __restrict__ Wk, const float* __restrict__ bk,
    const float* __restrict__ Wv, const float* __restrict__ bv,
    const float* __restrict__ Wo, float* __restrict__ out)
{
    const int z = blockIdx.x;
    const int h = z & 7;
    const int b = z >> 3;
    const int tid = threadIdx.x;

    __shared__ float s_sb[DM];
    __shared__ float s_red[64][4];
    __shared__ float s_kb[64], s_vb[64];
    __shared__ float s_part[T_KEEP][8];
    __shared__ float s_gp[64][4];
    __shared__ float s_G[64];
    __shared__ float s_cw[T_KEEP];

    s_sb[tid]       = sbar[z*DM + tid];
    s_sb[tid + 256] = sbar[z*DM + 256 + tid];
    __syncthreads();
    const float S = Ssum[z];

    // kbar = Wk_h * sbar + bk*S  (4 threads per output j)
    {
        int j = tid >> 2, kp = tid & 3;
        const float* wr = &Wk[(size_t)(h*HD + j)*DM + kp*128];
        float a = 0.f;
        #pragma unroll
        for (int k = 0; k < 128; k += 4) {
            float4 w4 = *(const float4*)&wr[k];
            int k0 = kp*128 + k;
            a += w4.x*s_sb[k0] + w4.y*s_sb[k0+1] + w4.z*s_sb[k0+2] + w4.w*s_sb[k0+3];
        }
        s_red[j][kp] = a;
    }
    __syncthreads();
    if (tid < 64) s_kb[tid] = s_red[tid][0]+s_red[tid][1]+s_red[tid][2]+s_red[tid][3]
                              + bk[h*HD + tid]*S;
    __syncthreads();
    // vbar = Wv_h * sbar + bv*S
    {
        int j = tid >> 2, kp = tid & 3;
        const float* wr = &Wv[(size_t)(h*HD + j)*DM + kp*128];
        float a = 0.f;
        #pragma unroll
        for (int k = 0; k < 128; k += 4) {
            float4 w4 = *(const float4*)&wr[k];
            int k0 = kp*128 + k;
            a += w4.x*s_sb[k0] + w4.y*s_sb[k0+1] + w4.z*s_sb[k0+2] + w4.w*s_sb[k0+3];
        }
        s_red[j][kp] = a;
    }
    __syncthreads();
    if (tid < 64) s_vb[tid] = s_red[tid][0]+s_red[tid][1]+s_red[tid][2]+s_red[tid][3]
                              + bv[h*HD + tid]*S;
    __syncthreads();

    // coef: scores via thread-parallel partials, softmax with sink
    {
        int wi = tid >> 3, jg = tid & 7;
        const float* qrow = &qsel[((size_t)z*T_KEEP + wi)*64 + jg*8];
        float4 q1 = *(const float4*)qrow;
        float4 q2 = *(const float4*)(qrow + 4);
        int j0 = jg*8;
        float p = q1.x*s_kb[j0] + q1.y*s_kb[j0+1] + q1.z*s_kb[j0+2] + q1.w*s_kb[j0+3]
                + q2.x*s_kb[j0+4] + q2.y*s_kb[j0+5] + q2.z*s_kb[j0+6] + q2.w*s_kb[j0+7];
        s_part[wi][jg] = p;
    }
    __syncthreads();
    if (tid < T_KEEP) {
        float sc = 0.f;
        #pragma unroll
        for (int gg = 0; gg < 8; ++gg) sc += s_part[tid][gg];
        sc *= 1.0f / (8.0f * expf(beta[h]));
        float m = sc;
        #pragma unroll
        for (int off = 16; off > 0; off >>= 1) m = fmaxf(m, __shfl_xor(m, off, 64));
        m = fmaxf(m, 0.f);                       // sink logit = 0
        float e = expf(sc - m);
        float d = e;
        #pragma unroll
        for (int off = 16; off > 0; off >>= 1) d += __shfl_xor(d, off, 64);
        d += expf(-m);                           // sink term
        float c = e / d;
        if (tid == T_KEEP-1) c += 1.0f;          // iter-0 contribution
        s_cw[tid] = c;
    }
    __syncthreads();

    // G in 8 passes of 64 cols; after each pass, atomically add
    // s_cw[wi]*G[c] into the 32 output rows of this z's batch b.
    const int cq = tid >> 2;
    const int jg = tid & 3;
    const int wi_a = tid >> 3;     // 0..31 for the atomic phase
    const int cg   = tid & 7;      // col-group (8 cols each)
    #pragma unroll
    for (int it = 0; it < 8; ++it) {
        int c = it*64 + cq;
        const float* wrow = &Wo[(size_t)c*DM + h*HD + jg*16];
        float a = 0.f;
        #pragma unroll
        for (int jj = 0; jj < 16; jj += 4) {
            float4 wv = *(const float4*)&wrow[jj];
            int j0 = jg*16 + jj;
            a += wv.x*s_vb[j0] + wv.y*s_vb[j0+1] + wv.z*s_vb[j0+2] + wv.w*s_vb[j0+3];
        }
        s_gp[cq][jg] = a;
        __syncthreads();
        if (tid < 64) s_G[tid] = s_gp[tid][0] + s_gp[tid][1] + s_gp[tid][2] + s_gp[tid][3];
        __syncthreads();
        {
            float cw = s_cw[wi_a];
            float* orow = &out[(size_t)(ROW0 + wi_a*2 + b)*DM + it*64 + cg*8];
            #pragma unroll
            for (int j = 0; j < 8; ++j)
                atomicAdd(&orow[j], cw * s_G[cg*8 + j]);
        }
        __syncthreads();
    }
}

extern "C" void kernel_launch(void* const* d_in, const int* in_sizes, int n_in,
                              void* d_out, int out_size, void* d_ws, size_t ws_size,
                              hipStream_t stream) {
    const float* x    = (const float*)d_in[0];
    const float* Wq   = (const float*)d_in[1];
    const float* bq   = (const float*)d_in[2];
    const float* Wk   = (const float*)d_in[3];
    const float* bk   = (const float*)d_in[4];
    const float* Wv   = (const float*)d_in[5];
    const float* bv   = (const float*)d_in[6];
    const float* Wo   = (const float*)d_in[7];
    const float* bo   = (const float*)d_in[8];
    const float* beta = (const float*)d_in[9];

    char* ws = (char*)d_ws;
    float* sig  = (float*)(ws + 0);         // 128 KB [h][4096] raw scores
    float* qsel = (float*)(ws + 131072);    // 128 KB
    float* sbar = (float*)(ws + 262144);    //  32 KB [z][512]
    float* Ssum = (float*)(ws + 294912);    //  64 B
    float* bcat = (float*)(ws + 295168);    //   4 KB [h][128] (q|k)
    short* xf   = (short*)(ws + 299264);    //   4 MB
    short* wf   = (short*)(ws + 299264 + 4194304);   // 1 MB
    float* out  = (float*)d_out;

    convert<<<2048, 256, 0, stream>>>(x, Wq, Wk, bq, bk, bo,
                                      xf, wf, bcat, sig, sbar, Ssum, out);
    dim3 g1(32, NH, 2);
    qk_gemm<<<g1, 256, 0, stream>>>((const _Float16*)xf, (const _Float16*)wf,
                                    bcat, sig, qsel);
    sbark<<<64, 256, 0, stream>>>(x, sig, beta, sbar, Ssum);
    headk_out<<<16, 256, 0, stream>>>(qsel, beta, sbar, Ssum, Wk, bk, Wv, bv, Wo, out);
}